// Round 3
// baseline (9303.872 us; speedup 1.0000x reference)
//
#include <hip/hip_runtime.h>

typedef _Float16 f16;
typedef _Float16 half2t __attribute__((ext_vector_type(2)));
typedef _Float16 half8 __attribute__((ext_vector_type(8)));
typedef float floatx4 __attribute__((ext_vector_type(4)));
typedef unsigned int uint;

#define B_ 128
#define S_ 1024
#define D_ 256
#define H_ 256
#define N3H 768

// ---------------------------------------------------------------------------
// Pack W_hh fp32 [256][768] -> uint-packed half2 along K: whh2[k2*768 + j]
// holds (W[2k2][j], W[2k2+1][j]) as two fp16 in one dword.
// ---------------------------------------------------------------------------
__global__ void pack_whh_kernel(const float* __restrict__ whh,
                                uint* __restrict__ whh2) {
  int idx = blockIdx.x * 256 + threadIdx.x;
  if (idx >= 128 * N3H) return;
  int k2 = idx / N3H;
  int j  = idx - k2 * N3H;
  f16 lo = (f16)whh[(2 * k2) * N3H + j];
  f16 hi = (f16)whh[(2 * k2 + 1) * N3H + j];
  uint v = ((uint)__builtin_bit_cast(unsigned short, lo)) |
           ((uint)__builtin_bit_cast(unsigned short, hi) << 16);
  whh2[idx] = v;
}

// ---------------------------------------------------------------------------
// Phase 1: gx[M=131072][768] = X[M][256] @ W_ih[256][768] + b_ih  (fp16 out)
// ---------------------------------------------------------------------------
__global__ __launch_bounds__(256) void gemm_gx_kernel(
    const float* __restrict__ X, const float* __restrict__ W,
    const float* __restrict__ bias, f16* __restrict__ gx) {
  __shared__ __align__(16) f16 As[128][40];  // [m][k], pad 32->40
  __shared__ __align__(16) f16 Bs[128][40];  // [n][k] (transposed on store)
  const int m0 = blockIdx.x * 128;
  const int n0 = blockIdx.y * 128;
  const int tid = threadIdx.x;
  const int lane = tid & 63, wave = tid >> 6;
  const int wr = (wave >> 1) * 64, wc = (wave & 1) * 64;
  const int quad = lane >> 4, l16 = lane & 15;

  floatx4 acc[4][4];
#pragma unroll
  for (int i = 0; i < 4; i++)
#pragma unroll
    for (int j = 0; j < 4; j++) acc[i][j] = (floatx4)0.f;

  const int arow = tid >> 1, akh = (tid & 1) * 16;
  const int bkr = tid >> 3, bns = (tid & 7) * 16;

  for (int k0 = 0; k0 < 256; k0 += 32) {
    __syncthreads();
    {
      const float* src = X + (size_t)(m0 + arow) * 256 + k0 + akh;
      float4 f0 = ((const float4*)src)[0];
      float4 f1 = ((const float4*)src)[1];
      float4 f2 = ((const float4*)src)[2];
      float4 f3 = ((const float4*)src)[3];
      half8 v0 = {(f16)f0.x, (f16)f0.y, (f16)f0.z, (f16)f0.w,
                  (f16)f1.x, (f16)f1.y, (f16)f1.z, (f16)f1.w};
      half8 v1 = {(f16)f2.x, (f16)f2.y, (f16)f2.z, (f16)f2.w,
                  (f16)f3.x, (f16)f3.y, (f16)f3.z, (f16)f3.w};
      *(half8*)&As[arow][akh] = v0;
      *(half8*)&As[arow][akh + 8] = v1;
    }
    {
      const float* src = W + (size_t)(k0 + bkr) * N3H + n0 + bns;
      float4 f0 = ((const float4*)src)[0];
      float4 f1 = ((const float4*)src)[1];
      float4 f2 = ((const float4*)src)[2];
      float4 f3 = ((const float4*)src)[3];
      float fv[16] = {f0.x, f0.y, f0.z, f0.w, f1.x, f1.y, f1.z, f1.w,
                      f2.x, f2.y, f2.z, f2.w, f3.x, f3.y, f3.z, f3.w};
#pragma unroll
      for (int i = 0; i < 16; ++i) Bs[bns + i][bkr] = (f16)fv[i];
    }
    __syncthreads();
    half8 a[4], b[4];
#pragma unroll
    for (int i = 0; i < 4; ++i) a[i] = *(const half8*)&As[wr + i * 16 + l16][quad * 8];
#pragma unroll
    for (int j = 0; j < 4; ++j) b[j] = *(const half8*)&Bs[wc + j * 16 + l16][quad * 8];
#pragma unroll
    for (int i = 0; i < 4; ++i)
#pragma unroll
      for (int j = 0; j < 4; ++j)
        acc[i][j] = __builtin_amdgcn_mfma_f32_16x16x32_f16(a[i], b[j], acc[i][j], 0, 0, 0);
  }
#pragma unroll
  for (int i = 0; i < 4; ++i) {
#pragma unroll
    for (int j = 0; j < 4; ++j) {
      int col = n0 + wc + j * 16 + l16;
      float bv = bias[col];
#pragma unroll
      for (int r = 0; r < 4; ++r) {
        int row = m0 + wr + i * 16 + quad * 4 + r;
        gx[(size_t)row * N3H + col] = (f16)(acc[i][j][r] + bv);
      }
    }
  }
}

__device__ __forceinline__ float fd2(uint h, uint w, float acc) {
  return __builtin_amdgcn_fdot2(__builtin_bit_cast(half2t, h),
                                __builtin_bit_cast(half2t, w), acc, false);
}

// ---------------------------------------------------------------------------
// Phase 2: recurrence. One block per batch; 512 threads (8 waves, 2/SIMD ->
// 256-VGPR cap). Thread t owns full gh column t (r for t<256, z for t>=256:
// 128 packed dwords) PLUS half (K-split by t>>8) of n-column (t&255): 64
// dwords. 192 weight dwords register-resident per thread. Partials combine
// via LDS; updater threads (t<256) do gates + h/out. h double-buffered fp16
// in LDS (broadcast reads), previous h kept in updater registers.
// ---------------------------------------------------------------------------
__global__ __launch_bounds__(512, 1) void gru_rec_kernel(
    const f16* __restrict__ gx,   // [128*1024][768]
    const uint* __restrict__ w2,  // [128][768] packed half2
    const float* __restrict__ bhh,
    const float* __restrict__ mask,
    float* __restrict__ out) {
  const int b = blockIdx.x;
  const int t = threadIdx.x;  // 0..511
  const int u = t & 255;
  const int half = t >> 8;  // wave-uniform

  __shared__ __align__(16) f16 h16[2][256];
  __shared__ float fullb[512];
  __shared__ float halfb[512];

  uint wf[128], wh[64];
#pragma unroll
  for (int k = 0; k < 128; ++k) wf[k] = w2[k * N3H + t];
#pragma unroll
  for (int k = 0; k < 64; ++k) wh[k] = w2[(64 * half + k) * N3H + 512 + u];

  const float bf = bhh[t];
  const float bn = bhh[512 + u];
  const f16* gxp = gx + (size_t)b * S_ * N3H;
  const float* mp = mask + (size_t)b * S_;
  float* outp = out + (size_t)b * S_ * H_ + u;

  float hreg = 0.f;
  if (t < 256) h16[0][u] = (f16)0.f;
  __syncthreads();

  float gxr = 0.f, gxz = 0.f, gxn = 0.f, m = 0.f;
  if (t < 256) {
    gxr = (float)gxp[u];
    gxz = (float)gxp[u + 256];
    gxn = (float)gxp[u + 512];
    m = mp[0];
  }

  for (int step = 0; step < S_; ++step) {
    // prefetch next step's gx/mask (updater threads only) during dot phase
    float ngxr = 0.f, ngxz = 0.f, ngxn = 0.f, nm = 0.f;
    if (t < 256 && step + 1 < S_) {
      const f16* np = gxp + (size_t)(step + 1) * N3H;
      ngxr = (float)np[u];
      ngxz = (float)np[u + 256];
      ngxn = (float)np[u + 512];
      nm = mp[step + 1];
    }

    const uint4* h4 = (const uint4*)&h16[step & 1][0];
    float af0 = 0.f, af1 = 0.f, ah0 = 0.f, ah1 = 0.f;
#pragma unroll
    for (int ch = 0; ch < 4; ++ch) {  // 4 chunks x 8 uint4 (64 halves each)
      uint4 c[8];
#pragma unroll
      for (int i = 0; i < 8; ++i) c[i] = h4[ch * 8 + i];
#pragma unroll
      for (int i = 0; i < 8; ++i) {
        const int k = (ch * 8 + i) * 4;
        af0 = fd2(c[i].x, wf[k + 0], af0);
        af1 = fd2(c[i].y, wf[k + 1], af1);
        af0 = fd2(c[i].z, wf[k + 2], af0);
        af1 = fd2(c[i].w, wf[k + 3], af1);
      }
      if ((ch >> 1) == half) {  // wave-uniform: this thread's n-half lives here
#pragma unroll
        for (int i = 0; i < 8; ++i) {
          const int k = ((ch & 1) * 8 + i) * 4;
          ah0 = fd2(c[i].x, wh[k + 0], ah0);
          ah1 = fd2(c[i].y, wh[k + 1], ah1);
          ah0 = fd2(c[i].z, wh[k + 2], ah0);
          ah1 = fd2(c[i].w, wh[k + 3], ah1);
        }
      }
    }

    fullb[t] = af0 + af1 + bf;
    halfb[t] = ah0 + ah1;
    __syncthreads();

    if (t < 256) {
      float ghr = fullb[u];
      float ghz = fullb[u + 256];
      float ghn = halfb[u] + halfb[u + 256] + bn;
      float xr = gxr + ghr;
      float xz = gxz + ghz;
      xr = fminf(fmaxf(xr, -30.f), 30.f);
      xz = fminf(fmaxf(xz, -30.f), 30.f);
      float r = 1.f / (1.f + __expf(-xr));
      float z = 1.f / (1.f + __expf(-xz));
      float xn = gxn + r * ghn;
      xn = fminf(fmaxf(xn, -15.f), 15.f);
      float e = __expf(2.f * xn);
      float n = (e - 1.f) / (e + 1.f);  // tanh
      float hp = hreg;
      float hnew = (1.f - z) * n + z * hp;
      float hv = m * hnew + (1.f - m) * hp;
      hreg = hv;
      h16[(step + 1) & 1][u] = (f16)hv;
      outp[(size_t)step * H_] = hv;
    }
    __syncthreads();

    gxr = ngxr;
    gxz = ngxz;
    gxn = ngxn;
    m = nm;
  }
}

// ---------------------------------------------------------------------------
extern "C" void kernel_launch(void* const* d_in, const int* in_sizes, int n_in,
                              void* d_out, int out_size, void* d_ws, size_t ws_size,
                              hipStream_t stream) {
  const float* x    = (const float*)d_in[0];
  const float* mask = (const float*)d_in[1];
  const float* Wih  = (const float*)d_in[2];
  const float* Whh  = (const float*)d_in[3];
  const float* bih  = (const float*)d_in[4];
  const float* bhh  = (const float*)d_in[5];
  float* out = (float*)d_out;

  // ws layout: gx16 (201.3 MB) | whh2 packed (384 KB)
  f16* gx = (f16*)d_ws;
  uint* whh2 = (uint*)((char*)d_ws + (size_t)B_ * S_ * N3H * sizeof(f16));

  pack_whh_kernel<<<dim3((128 * N3H + 255) / 256), dim3(256), 0, stream>>>(Whh, whh2);
  gemm_gx_kernel<<<dim3((B_ * S_) / 128, N3H / 128), dim3(256), 0, stream>>>(x, Wih, bih, gx);
  gru_rec_kernel<<<dim3(B_), dim3(512), 0, stream>>>(gx, whh2, bhh, mask, out);
}